// Round 5
// baseline (1041.194 us; speedup 1.0000x reference)
//
#include <hip/hip_runtime.h>

// GAT fused pipeline, fp16 MFMA (16x16x32), MI355X gfx950.
// B=16, N=1024, F_in=F_out=256, H=8, ALPHA=0.2
//
// Round-11: pv's residual ~30us is DMA-path stall (contended L2: per XCD
// 16bh x 512KB = 8MB working set in 4MB L2; prefetch depth didn't help in
// R9 -> traffic-bound, not latency). Structural fix: the Bp (WhT) chunk is
// IDENTICAL for all it of a bh, so merge 2 i-tiles per block:
//  - 512 thr / 8 waves, block tile 256i x 256o, grid (128 bh, 4 it2).
//  - WhT re-read traffic halves (512->256 MB); per-thread work, acc[4][8],
//    and P-gen totals unchanged.
//  - 512 blocks = exactly 2 rounds of 256 (no ragged 768+256 tail);
//    16 waves/CU (was ~12). LDS 70.7KB -> 2 blocks/CU.
//  - launch_bounds(512,4) pins VGPR<=128 (R10 compiled to 124, same tiling).
// pv R10 counters: 98us, Mfma 30%, VALU 39%, conflicts 0, FETCH 73MB.
//
// ws: [0,64MB) WhT fp16 [B][H][F_out][N]; +67108864 eiP[2][128K] f32;
//     +68157440 ejP[2][128K] f32. Total 66 MiB.

#define L2E 1.442695041f

typedef _Float16 half8 __attribute__((ext_vector_type(8)));
typedef __fp16 fp16x2 __attribute__((ext_vector_type(2)));
typedef float floatx4 __attribute__((ext_vector_type(4)));

#if __has_builtin(__builtin_amdgcn_exp2f)
#define EXP2F(x) __builtin_amdgcn_exp2f(x)
#else
#define EXP2F(x) exp2f(x)
#endif

#if __has_builtin(__builtin_amdgcn_rcpf)
#define RCPF(x) __builtin_amdgcn_rcpf(x)
#else
#define RCPF(x) (1.0f / (x))
#endif

static __device__ inline unsigned int pack2(float a, float b) {
    fp16x2 h = __builtin_amdgcn_cvt_pkrtz(a, b);
    return __builtin_bit_cast(unsigned int, h);
}

typedef __attribute__((address_space(1))) const void GV;
typedef __attribute__((address_space(3))) void LV;
static __device__ inline void load_lds16(const void* g, void* l) {
    __builtin_amdgcn_global_load_lds((GV*)g, (LV*)l, 16, 0, 0);
}

// 64B-row swizzle (wh tiles): chunk c of 16B, c' = c ^ ((row>>1)&3)
static __device__ inline int swz(int row, int c) {
    return (row << 6) + ((((c) ^ (row >> 1)) & 3) << 4);
}
// 128B-row swizzle (pv tiles): 8 chunks of 16B, c' = c ^ (row&7)
static __device__ inline int swz128(int row, int c) {
    return (row << 7) + ((((c) ^ row) & 7) << 4);
}

// ---------------------------------------------------------------------------
// Stage 1: WhT[b,h,o,n] = sum_f W[h,o,f]*h[b,n,f] + bW[h,o]  (fp16 out)
// + per-ot ei/ej partial epilogue. Tile 128(o) x 128(bn), K=256, BK=32.
// (unchanged from round-10)
__global__ __launch_bounds__(256, 3) void wh_kernel(
    const float* __restrict__ hin, const float* __restrict__ W,
    const float* __restrict__ bW, _Float16* __restrict__ WhT,
    const float* __restrict__ a1, const float* __restrict__ a2,
    float* __restrict__ eiP, float* __restrict__ ejP)
{
    const int bnt  = blockIdx.x;   // 0..127
    const int ot   = blockIdx.y;   // 0..1
    const int head = blockIdx.z;   // 0..7
    const int t    = threadIdx.x;
    const int wave = t >> 6, lane = t & 63;
    const int l15 = lane & 15, quad = lane >> 4;
    const int wmh = wave & 1, wnh = wave >> 1;

    __shared__ char smem[16384];
    _Float16* As = (_Float16*)smem;            // 128 rows x 64B = 8192
    _Float16* Bs = (_Float16*)(smem + 8192);   // 128 rows x 64B = 8192
    // epilogue overlay (tiles dead after K-loop):
    float* bWs   = (float*)smem;               // 128 f32
    float* a1s   = (float*)(smem + 512);
    float* a2s   = (float*)(smem + 1024);
    float* part1 = (float*)(smem + 1536);      // [2 wmh][128 row] = 1KB
    float* part2 = (float*)(smem + 2560);      // 1KB

    const int o0 = ot * 128;
    const int bn0 = bnt * 128;
    floatx4 acc[4][4];
#pragma unroll
    for (int a = 0; a < 4; a++)
#pragma unroll
        for (int b = 0; b < 4; b++) acc[a][b] = (floatx4)0.0f;

    const int ar = t >> 1, ah = t & 1;   // staging: row, 16-float half
    const float* Wrow = W + (size_t)(head * 256 + o0 + ar) * 256 + ah * 16;
    const float* hrow = hin + (size_t)(bn0 + ar) * 256 + ah * 16;

    float4 pa0, pa1, pa2, pa3, pb0, pb1, pb2, pb3;
    {
        const float4* p4 = (const float4*)Wrow;
        pa0 = p4[0]; pa1 = p4[1]; pa2 = p4[2]; pa3 = p4[3];
        const float4* q4 = (const float4*)hrow;
        pb0 = q4[0]; pb1 = q4[1]; pb2 = q4[2]; pb3 = q4[3];
    }

    for (int f0 = 0; f0 < 256; f0 += 32) {
        __syncthreads();
        *(uint4*)((char*)As + swz(ar, 2 * ah)) =
            make_uint4(pack2(pa0.x, pa0.y), pack2(pa0.z, pa0.w),
                       pack2(pa1.x, pa1.y), pack2(pa1.z, pa1.w));
        *(uint4*)((char*)As + swz(ar, 2 * ah + 1)) =
            make_uint4(pack2(pa2.x, pa2.y), pack2(pa2.z, pa2.w),
                       pack2(pa3.x, pa3.y), pack2(pa3.z, pa3.w));
        *(uint4*)((char*)Bs + swz(ar, 2 * ah)) =
            make_uint4(pack2(pb0.x, pb0.y), pack2(pb0.z, pb0.w),
                       pack2(pb1.x, pb1.y), pack2(pb1.z, pb1.w));
        *(uint4*)((char*)Bs + swz(ar, 2 * ah + 1)) =
            make_uint4(pack2(pb2.x, pb2.y), pack2(pb2.z, pb2.w),
                       pack2(pb3.x, pb3.y), pack2(pb3.z, pb3.w));
        if (f0 < 224) {   // prefetch next chunk
            const float4* p4 = (const float4*)(Wrow + f0 + 32);
            pa0 = p4[0]; pa1 = p4[1]; pa2 = p4[2]; pa3 = p4[3];
            const float4* q4 = (const float4*)(hrow + f0 + 32);
            pb0 = q4[0]; pb1 = q4[1]; pb2 = q4[2]; pb3 = q4[3];
        }
        __syncthreads();
        half8 af[4], bf[4];
#pragma unroll
        for (int a = 0; a < 4; a++)
            af[a] = *(const half8*)((char*)As + swz(wmh * 64 + a * 16 + l15, quad));
#pragma unroll
        for (int b = 0; b < 4; b++)
            bf[b] = *(const half8*)((char*)Bs + swz(wnh * 64 + b * 16 + l15, quad));
#pragma unroll
        for (int a = 0; a < 4; a++)
#pragma unroll
            for (int b = 0; b < 4; b++)
                acc[a][b] = __builtin_amdgcn_mfma_f32_16x16x32_f16(af[a], bf[b], acc[a][b], 0, 0, 0);
    }

    __syncthreads();   // tiles dead; overlay epilogue arrays
    if (t < 128) {
        bWs[t] = bW[head * 256 + o0 + t];
        a1s[t] = a1[head * 256 + o0 + t];
        a2s[t] = a2[head * 256 + o0 + t];
    }
    __syncthreads();

    const int bidx = bn0 >> 10;     // batch index (tile never crosses batch)
    const int nbase = bn0 & 1023;
#pragma unroll
    for (int b = 0; b < 4; b++) {
        const int bnl = wnh * 64 + b * 16 + l15;   // local bn 0..127
        const int n = nbase + bnl;
        float p1 = 0.f, p2 = 0.f;
#pragma unroll
        for (int a = 0; a < 4; a++) {
#pragma unroll
            for (int r = 0; r < 4; r++) {
                int ol = wmh * 64 + a * 16 + quad * 4 + r;   // local o
                float v = acc[a][b][r] + bWs[ol];
                WhT[(((size_t)(bidx * 8 + head) * 256 + o0 + ol) << 10) + n] = (_Float16)v;
                p1 = fmaf(v, a1s[ol], p1);
                p2 = fmaf(v, a2s[ol], p2);
            }
        }
        p1 += __shfl_xor(p1, 16, 64); p1 += __shfl_xor(p1, 32, 64);
        p2 += __shfl_xor(p2, 16, 64); p2 += __shfl_xor(p2, 32, 64);
        if (lane < 16) {
            part1[wmh * 128 + bnl] = p1;
            part2[wmh * 128 + bnl] = p2;
        }
    }
    __syncthreads();
    if (t < 128) {
        float s1 = part1[t] + part1[128 + t];
        float s2 = part2[t] + part2[128 + t];
        const size_t idx = (size_t)(bidx * 8 + head) * 1024 + nbase + t;
        eiP[(size_t)ot * 131072 + idx] = s1;
        ejP[(size_t)ot * 131072 + idx] = s2;
    }
}

// ---------------------------------------------------------------------------
// Stage 2: out[b,i,h*256+o] = sigmoid(relu( (1/l_i) * sum_j p~_ij * Wh[j,o] ))
// p~ = exp2(max(A+ej', fma(.2,ej',Bc))), A=cip+nm, Bc=.2cip+nm (pre-folded).
// Tile 256(i) x 256(o) per block: Bp (WhT chunk) staged ONCE serves both
// 128-i halves. 512 thr = 8 waves: wmh = wave>>1 over i (4x64),
// wnh = wave&1 over o (2x128). acc[4][8]/wave (unchanged per-thread).
// K=1024 in BK=64. B staged via global_load_lds (pre-swizzled source).
__global__ __launch_bounds__(512, 4) void pv_kernel(
    const _Float16* __restrict__ WhT, const float* __restrict__ eiP,
    const float* __restrict__ ejP, const float* __restrict__ bA,
    float* __restrict__ out)
{
    const int bh  = blockIdx.x;   // 0..127 (fast dim -> XCD key; all 4 it2
                                  //  blocks of one bh land on XCD bh%8)
    const int it2 = blockIdx.y;   // 0..3
    const int b = bh >> 3, head = bh & 7;
    const int t = threadIdx.x;
    const int wave = t >> 6, lane = t & 63;
    const int l15 = lane & 15, quad = lane >> 4;
    const int wmh = wave >> 1, wnh = wave & 1;   // i-quarter / o-half

    __shared__ char smem[70688];
    _Float16* Ap = (_Float16*)smem;             // P: 256 rows x 128B = 32768
    _Float16* Bp = (_Float16*)(smem + 32768);   // WhT: 256 rows x 128B = 32768
    float* ejs  = (float*)(smem + 65536);       // 1024 f32 (*L2E) 4KB
    float* lns  = (float*)(smem + 69632);       // 256 denominators 1KB
    float* wred = (float*)(smem + 70656);       // 8 wave maxes

    // preamble: ej = ej0+ej1 (ot halves), stage *L2E, block max
    const float* ej0 = ejP + bh * 1024;
    const float* ej1 = ejP + 131072 + bh * 1024;
    float mx = -1e30f;
#pragma unroll
    for (int k = 0; k < 2; k++) {
        int idx = t + k * 512;
        float v = (ej0[idx] + ej1[idx]) * L2E;
        ejs[idx] = v;
        mx = fmaxf(mx, v);
    }
#pragma unroll
    for (int m = 32; m; m >>= 1) mx = fmaxf(mx, __shfl_xor(mx, m, 64));
    if (lane == 0) wred[wave] = mx;
    __syncthreads();
    float ejmax = wred[0];
#pragma unroll
    for (int w = 1; w < 8; w++) ejmax = fmaxf(ejmax, wred[w]);

    const int i0 = it2 * 256;
    const int prow = t >> 1, pjh = t & 1;   // P-gen: row (0..255), 32-j half
    const float cip = (eiP[bh * 1024 + i0 + prow] +
                       eiP[131072 + bh * 1024 + i0 + prow] + bA[head]) * L2E;
    const float tmv = cip + ejmax;
    const float nm = -fmaxf(tmv, 0.2f * tmv);   // -m*log2e
    const float Ac = cip + nm;                  // folds nm into both branches
    const float Bc = fmaf(0.2f, cip, nm);       // max(e,.2e)+nm = max(Ac+ev, .2ev+Bc)

    // B staging via global_load_lds: wave w covers o-rows [w*32, w*32+32),
    // 4 instrs x 8 rows. LDS dest linear (HW writes lane*16); source
    // pre-swizzled so LDS chunk pos cp holds global chunk cp^(row&7)
    // -> read side uses swz128. row&7 == lane>>3 (q*8, w*32 are 0 mod 8).
    const int rsub = lane >> 3, cp7 = lane & 7;
    const _Float16* bsrc = WhT + ((size_t)bh << 18)
                         + ((size_t)(wave * 32 + rsub) << 10)
                         + ((cp7 ^ rsub) << 3);
    char* bdst0 = (char*)Bp + wave * 4096;

    floatx4 acc[4][8], accl[4];
#pragma unroll
    for (int a = 0; a < 4; a++) {
        accl[a] = (floatx4)0.0f;
#pragma unroll
        for (int c = 0; c < 8; c++) acc[a][c] = (floatx4)0.0f;
    }
    const bool doL = (wnh == 0);   // waves 0,2,4,6 cover all 256 i rows
    const half8 ones = {1, 1, 1, 1, 1, 1, 1, 1};

    for (int j0 = 0; j0 < 1024; j0 += 64) {
        __syncthreads();
        // issue B loads first: P-gen's exp VALU stretch hides DMA latency
#pragma unroll
        for (int q = 0; q < 4; q++)
            load_lds16(bsrc + j0 + q * 8192, bdst0 + q * 1024);
        {   // P-gen: 32 exps -> 4 swizzled uint4 (ej read = LDS broadcast)
            const float4* ejp4 = (const float4*)(ejs + j0 + pjh * 32);
#pragma unroll
            for (int q = 0; q < 4; q++) {
                float4 e4a = ejp4[2 * q], e4b = ejp4[2 * q + 1];
                float p[8];
                const float ev[8] = {e4a.x, e4a.y, e4a.z, e4a.w,
                                     e4b.x, e4b.y, e4b.z, e4b.w};
#pragma unroll
                for (int u = 0; u < 8; u++) {
                    float t1 = Ac + ev[u];
                    float t2 = fmaf(0.2f, ev[u], Bc);
                    p[u] = EXP2F(fmaxf(t1, t2));
                }
                *(uint4*)((char*)Ap + swz128(prow, pjh * 4 + q)) =
                    make_uint4(pack2(p[0], p[1]), pack2(p[2], p[3]),
                               pack2(p[4], p[5]), pack2(p[6], p[7]));
            }
        }
        __syncthreads();   // drains vmcnt (global_load_lds) + lgkm (Ap writes)
#pragma unroll
        for (int kk = 0; kk < 2; kk++) {
            half8 af[4], bf[8];
#pragma unroll
            for (int a = 0; a < 4; a++)
                af[a] = *(const half8*)((char*)Ap + swz128(wmh * 64 + a * 16 + l15, kk * 4 + quad));
#pragma unroll
            for (int c = 0; c < 8; c++)
                bf[c] = *(const half8*)((char*)Bp + swz128(wnh * 128 + c * 16 + l15, kk * 4 + quad));
            if (doL) {
#pragma unroll
                for (int a = 0; a < 4; a++)
                    accl[a] = __builtin_amdgcn_mfma_f32_16x16x32_f16(af[a], ones, accl[a], 0, 0, 0);
            }
#pragma unroll
            for (int a = 0; a < 4; a++)
#pragma unroll
                for (int c = 0; c < 8; c++)
                    acc[a][c] = __builtin_amdgcn_mfma_f32_16x16x32_f16(af[a], bf[c], acc[a][c], 0, 0, 0);
        }
    }

    __syncthreads();
    if (doL && l15 == 0) {   // all 16 cols identical; publish row sums
#pragma unroll
        for (int a = 0; a < 4; a++)
#pragma unroll
            for (int r = 0; r < 4; r++)
                lns[wmh * 64 + a * 16 + quad * 4 + r] = accl[a][r];
    }
    __syncthreads();

    // rs = -L2E / l  (raw v_rcp; rel err ~1e-5 << tolerance)
    float rs[4][4];
#pragma unroll
    for (int a = 0; a < 4; a++)
#pragma unroll
        for (int r = 0; r < 4; r++)
            rs[a][r] = -L2E * RCPF(lns[wmh * 64 + a * 16 + quad * 4 + r]);

#pragma unroll
    for (int a = 0; a < 4; a++) {
#pragma unroll
        for (int c = 0; c < 8; c++) {
            int o = wnh * 128 + c * 16 + l15;
#pragma unroll
            for (int r = 0; r < 4; r++) {
                int i = i0 + wmh * 64 + a * 16 + quad * 4 + r;
                // sigmoid(relu(v)) = rcp(1 + exp2(min(v*(-L2E/l), 0)))
                float tx = fminf(acc[a][c][r] * rs[a][r], 0.0f);
                float y = RCPF(1.0f + EXP2F(tx));
                out[((size_t)(b * 1024 + i) << 11) + head * 256 + o] = y;
            }
        }
    }
}

// ---------------------------------------------------------------------------
extern "C" void kernel_launch(void* const* d_in, const int* in_sizes, int n_in,
                              void* d_out, int out_size, void* d_ws, size_t ws_size,
                              hipStream_t stream)
{
    const float* h  = (const float*)d_in[0];
    const float* W  = (const float*)d_in[1];
    const float* bW = (const float*)d_in[2];
    const float* a1 = (const float*)d_in[3];
    const float* a2 = (const float*)d_in[4];
    const float* bA = (const float*)d_in[5];
    float* out = (float*)d_out;

    char* ws = (char*)d_ws;
    _Float16* WhT = (_Float16*)ws;                       // 67108864 B
    float* eiP = (float*)(ws + 67108864);                // 2 x 524288 B
    float* ejP = (float*)(ws + 67108864 + 1048576);      // 2 x 524288 B

    hipLaunchKernelGGL(wh_kernel, dim3(128, 2, 8), dim3(256), 0, stream,
                       h, W, bW, WhT, a1, a2, eiP, ejP);
    hipLaunchKernelGGL(pv_kernel, dim3(128, 4), dim3(512), 0, stream,
                       WhT, eiP, ejP, bA, out);
}

// Round 6
// 283.767 us; speedup vs baseline: 3.6692x; 3.6692x over previous
//
#include <hip/hip_runtime.h>

// GAT fused pipeline, fp16 MFMA (16x16x32), MI355X gfx950.
// B=16, N=1024, F_in=F_out=256, H=8, ALPHA=0.2
//
// Round-12: R11 spilled (launch_bounds(512,4) = 128-reg cap vs ~190-reg
// per-thread state -> acc spilled, 2.6GB scratch, 9x regression). Keep the
// Bp-traffic-halving 256i x 256o tile but fix register geometry:
//  - 1024 thr / 16 waves as 4i x 4o -> per-wave 64x64, acc[4][4]=64 regs,
//    peak ~110 < 128 cap implied by 1024-thr block. No spill.
//  - l_i computed during P-gen (lsum + 2 shfl_xor, 4 thr/row): removes the
//    ones-MFMA (-10% MFMA) and accl regs. (f32-vs-fp16 p-sum bias ~2^-12
//    relative -> ~6e-5 on output, << 3.9e-3 absmax.)
//  - P-gen 16 exps/thread; Bp staged once per chunk serves all 256 i-rows
//    (WhT re-read 512->256 MB at L2/L3 level).
//  - grid (128 bh, 4) = 512 blocks = 2 clean rounds; 16 waves/CU.
// R10 reference: pv 98us, Mfma 30%, VALU 39%; R11: spill disaster.
//
// ws: [0,64MB) WhT fp16 [B][H][F_out][N]; +67108864 eiP[2][128K] f32;
//     +68157440 ejP[2][128K] f32. Total 66 MiB.

#define L2E 1.442695041f

typedef _Float16 half8 __attribute__((ext_vector_type(8)));
typedef __fp16 fp16x2 __attribute__((ext_vector_type(2)));
typedef float floatx4 __attribute__((ext_vector_type(4)));

#if __has_builtin(__builtin_amdgcn_exp2f)
#define EXP2F(x) __builtin_amdgcn_exp2f(x)
#else
#define EXP2F(x) exp2f(x)
#endif

#if __has_builtin(__builtin_amdgcn_rcpf)
#define RCPF(x) __builtin_amdgcn_rcpf(x)
#else
#define RCPF(x) (1.0f / (x))
#endif

static __device__ inline unsigned int pack2(float a, float b) {
    fp16x2 h = __builtin_amdgcn_cvt_pkrtz(a, b);
    return __builtin_bit_cast(unsigned int, h);
}

typedef __attribute__((address_space(1))) const void GV;
typedef __attribute__((address_space(3))) void LV;
static __device__ inline void load_lds16(const void* g, void* l) {
    __builtin_amdgcn_global_load_lds((GV*)g, (LV*)l, 16, 0, 0);
}

// 64B-row swizzle (wh tiles): chunk c of 16B, c' = c ^ ((row>>1)&3)
static __device__ inline int swz(int row, int c) {
    return (row << 6) + ((((c) ^ (row >> 1)) & 3) << 4);
}
// 128B-row swizzle (pv tiles): 8 chunks of 16B, c' = c ^ (row&7)
static __device__ inline int swz128(int row, int c) {
    return (row << 7) + ((((c) ^ row) & 7) << 4);
}

// ---------------------------------------------------------------------------
// Stage 1: WhT[b,h,o,n] = sum_f W[h,o,f]*h[b,n,f] + bW[h,o]  (fp16 out)
// + per-ot ei/ej partial epilogue. Tile 128(o) x 128(bn), K=256, BK=32.
// (unchanged from round-10)
__global__ __launch_bounds__(256, 3) void wh_kernel(
    const float* __restrict__ hin, const float* __restrict__ W,
    const float* __restrict__ bW, _Float16* __restrict__ WhT,
    const float* __restrict__ a1, const float* __restrict__ a2,
    float* __restrict__ eiP, float* __restrict__ ejP)
{
    const int bnt  = blockIdx.x;   // 0..127
    const int ot   = blockIdx.y;   // 0..1
    const int head = blockIdx.z;   // 0..7
    const int t    = threadIdx.x;
    const int wave = t >> 6, lane = t & 63;
    const int l15 = lane & 15, quad = lane >> 4;
    const int wmh = wave & 1, wnh = wave >> 1;

    __shared__ char smem[16384];
    _Float16* As = (_Float16*)smem;            // 128 rows x 64B = 8192
    _Float16* Bs = (_Float16*)(smem + 8192);   // 128 rows x 64B = 8192
    // epilogue overlay (tiles dead after K-loop):
    float* bWs   = (float*)smem;               // 128 f32
    float* a1s   = (float*)(smem + 512);
    float* a2s   = (float*)(smem + 1024);
    float* part1 = (float*)(smem + 1536);      // [2 wmh][128 row] = 1KB
    float* part2 = (float*)(smem + 2560);      // 1KB

    const int o0 = ot * 128;
    const int bn0 = bnt * 128;
    floatx4 acc[4][4];
#pragma unroll
    for (int a = 0; a < 4; a++)
#pragma unroll
        for (int b = 0; b < 4; b++) acc[a][b] = (floatx4)0.0f;

    const int ar = t >> 1, ah = t & 1;   // staging: row, 16-float half
    const float* Wrow = W + (size_t)(head * 256 + o0 + ar) * 256 + ah * 16;
    const float* hrow = hin + (size_t)(bn0 + ar) * 256 + ah * 16;

    float4 pa0, pa1, pa2, pa3, pb0, pb1, pb2, pb3;
    {
        const float4* p4 = (const float4*)Wrow;
        pa0 = p4[0]; pa1 = p4[1]; pa2 = p4[2]; pa3 = p4[3];
        const float4* q4 = (const float4*)hrow;
        pb0 = q4[0]; pb1 = q4[1]; pb2 = q4[2]; pb3 = q4[3];
    }

    for (int f0 = 0; f0 < 256; f0 += 32) {
        __syncthreads();
        *(uint4*)((char*)As + swz(ar, 2 * ah)) =
            make_uint4(pack2(pa0.x, pa0.y), pack2(pa0.z, pa0.w),
                       pack2(pa1.x, pa1.y), pack2(pa1.z, pa1.w));
        *(uint4*)((char*)As + swz(ar, 2 * ah + 1)) =
            make_uint4(pack2(pa2.x, pa2.y), pack2(pa2.z, pa2.w),
                       pack2(pa3.x, pa3.y), pack2(pa3.z, pa3.w));
        *(uint4*)((char*)Bs + swz(ar, 2 * ah)) =
            make_uint4(pack2(pb0.x, pb0.y), pack2(pb0.z, pb0.w),
                       pack2(pb1.x, pb1.y), pack2(pb1.z, pb1.w));
        *(uint4*)((char*)Bs + swz(ar, 2 * ah + 1)) =
            make_uint4(pack2(pb2.x, pb2.y), pack2(pb2.z, pb2.w),
                       pack2(pb3.x, pb3.y), pack2(pb3.z, pb3.w));
        if (f0 < 224) {   // prefetch next chunk
            const float4* p4 = (const float4*)(Wrow + f0 + 32);
            pa0 = p4[0]; pa1 = p4[1]; pa2 = p4[2]; pa3 = p4[3];
            const float4* q4 = (const float4*)(hrow + f0 + 32);
            pb0 = q4[0]; pb1 = q4[1]; pb2 = q4[2]; pb3 = q4[3];
        }
        __syncthreads();
        half8 af[4], bf[4];
#pragma unroll
        for (int a = 0; a < 4; a++)
            af[a] = *(const half8*)((char*)As + swz(wmh * 64 + a * 16 + l15, quad));
#pragma unroll
        for (int b = 0; b < 4; b++)
            bf[b] = *(const half8*)((char*)Bs + swz(wnh * 64 + b * 16 + l15, quad));
#pragma unroll
        for (int a = 0; a < 4; a++)
#pragma unroll
            for (int b = 0; b < 4; b++)
                acc[a][b] = __builtin_amdgcn_mfma_f32_16x16x32_f16(af[a], bf[b], acc[a][b], 0, 0, 0);
    }

    __syncthreads();   // tiles dead; overlay epilogue arrays
    if (t < 128) {
        bWs[t] = bW[head * 256 + o0 + t];
        a1s[t] = a1[head * 256 + o0 + t];
        a2s[t] = a2[head * 256 + o0 + t];
    }
    __syncthreads();

    const int bidx = bn0 >> 10;     // batch index (tile never crosses batch)
    const int nbase = bn0 & 1023;
#pragma unroll
    for (int b = 0; b < 4; b++) {
        const int bnl = wnh * 64 + b * 16 + l15;   // local bn 0..127
        const int n = nbase + bnl;
        float p1 = 0.f, p2 = 0.f;
#pragma unroll
        for (int a = 0; a < 4; a++) {
#pragma unroll
            for (int r = 0; r < 4; r++) {
                int ol = wmh * 64 + a * 16 + quad * 4 + r;   // local o
                float v = acc[a][b][r] + bWs[ol];
                WhT[(((size_t)(bidx * 8 + head) * 256 + o0 + ol) << 10) + n] = (_Float16)v;
                p1 = fmaf(v, a1s[ol], p1);
                p2 = fmaf(v, a2s[ol], p2);
            }
        }
        p1 += __shfl_xor(p1, 16, 64); p1 += __shfl_xor(p1, 32, 64);
        p2 += __shfl_xor(p2, 16, 64); p2 += __shfl_xor(p2, 32, 64);
        if (lane < 16) {
            part1[wmh * 128 + bnl] = p1;
            part2[wmh * 128 + bnl] = p2;
        }
    }
    __syncthreads();
    if (t < 128) {
        float s1 = part1[t] + part1[128 + t];
        float s2 = part2[t] + part2[128 + t];
        const size_t idx = (size_t)(bidx * 8 + head) * 1024 + nbase + t;
        eiP[(size_t)ot * 131072 + idx] = s1;
        ejP[(size_t)ot * 131072 + idx] = s2;
    }
}

// ---------------------------------------------------------------------------
// Stage 2: out[b,i,h*256+o] = sigmoid(relu( (1/l_i) * sum_j p~_ij * Wh[j,o] ))
// p~ = exp2(max(Ac+ej', fma(.2,ej',Bc))); l_i summed during P-gen.
// Tile 256(i) x 256(o) per block, 1024 thr = 16 waves as 4(i) x 4(o):
// per-wave 64x64, acc[4][4]. K=1024 in BK=64; Bp staged once per chunk
// serves all 256 i rows. B staged via global_load_lds (pre-swz source).
__global__ __launch_bounds__(1024) void pv_kernel(
    const _Float16* __restrict__ WhT, const float* __restrict__ eiP,
    const float* __restrict__ ejP, const float* __restrict__ bA,
    float* __restrict__ out)
{
    const int bh  = blockIdx.x;   // 0..127 (fast dim; all 4 it2 blocks of a
                                  //  bh land on XCD bh%8: 128%8==0)
    const int it2 = blockIdx.y;   // 0..3
    const int b = bh >> 3, head = bh & 7;
    const int t = threadIdx.x;
    const int wave = t >> 6, lane = t & 63;
    const int l15 = lane & 15, quad = lane >> 4;
    const int wi = wave >> 2, wo = wave & 3;   // i-quarter / o-quarter

    __shared__ char smem[70720];
    _Float16* Ap = (_Float16*)smem;             // P: 256 rows x 128B = 32768
    _Float16* Bp = (_Float16*)(smem + 32768);   // WhT: 256 rows x 128B = 32768
    float* ejs  = (float*)(smem + 65536);       // 1024 f32 (*L2E) 4KB
    float* lns  = (float*)(smem + 69632);       // 256 denominators 1KB
    float* wred = (float*)(smem + 70656);       // 16 wave maxes

    // preamble: ej = ej0+ej1 (ot halves), stage *L2E, block max
    const float* ej0 = ejP + bh * 1024;
    const float* ej1 = ejP + 131072 + bh * 1024;
    float mx;
    {
        float v = (ej0[t] + ej1[t]) * L2E;
        ejs[t] = v;
        mx = v;
    }
#pragma unroll
    for (int m = 32; m; m >>= 1) mx = fmaxf(mx, __shfl_xor(mx, m, 64));
    if (lane == 0) wred[wave] = mx;
    __syncthreads();
    float ejmax = wred[0];
#pragma unroll
    for (int w = 1; w < 16; w++) ejmax = fmaxf(ejmax, wred[w]);

    const int i0 = it2 * 256;
    const int prow = t >> 2, pjh = t & 3;   // P-gen: row (0..255), 16-j quarter
    const float cip = (eiP[bh * 1024 + i0 + prow] +
                       eiP[131072 + bh * 1024 + i0 + prow] + bA[head]) * L2E;
    const float tmv = cip + ejmax;
    const float nm = -fmaxf(tmv, 0.2f * tmv);   // -m*log2e
    const float Ac = cip + nm;                  // folds nm into both branches
    const float Bc = fmaf(0.2f, cip, nm);       // max(e,.2e)+nm = max(Ac+ev, .2ev+Bc)

    // B staging via global_load_lds: wave w covers o-rows [w*16, w*16+16),
    // 2 instrs x 8 rows. LDS dest linear (HW writes base + lane*16); source
    // pre-swizzled so LDS chunk pos cp holds global chunk cp^(row&7)
    // -> read side uses swz128. row&7 == lane>>3 (q*8, w*16 are 0 mod 8).
    const int rsub = lane >> 3, cp7 = lane & 7;
    const _Float16* bsrc = WhT + ((size_t)bh << 18)
                         + ((size_t)(wave * 16 + rsub) << 10)
                         + ((cp7 ^ rsub) << 3);
    char* bdst0 = (char*)Bp + wave * 2048;

    floatx4 acc[4][4];
#pragma unroll
    for (int a = 0; a < 4; a++)
#pragma unroll
        for (int c = 0; c < 4; c++) acc[a][c] = (floatx4)0.0f;
    float lsum = 0.0f;

    for (int j0 = 0; j0 < 1024; j0 += 64) {
        __syncthreads();
        // issue B loads first: P-gen's exp VALU stretch hides DMA latency
#pragma unroll
        for (int q = 0; q < 2; q++)
            load_lds16(bsrc + j0 + q * 8192, bdst0 + q * 1024);
        {   // P-gen: 16 exps -> 2 swizzled uint4; accumulate lsum
            const float4* ejp4 = (const float4*)(ejs + j0 + pjh * 16);
#pragma unroll
            for (int q = 0; q < 2; q++) {
                float4 e4a = ejp4[2 * q], e4b = ejp4[2 * q + 1];
                float p[8];
                const float ev[8] = {e4a.x, e4a.y, e4a.z, e4a.w,
                                     e4b.x, e4b.y, e4b.z, e4b.w};
#pragma unroll
                for (int u = 0; u < 8; u++) {
                    float t1 = Ac + ev[u];
                    float t2 = fmaf(0.2f, ev[u], Bc);
                    p[u] = EXP2F(fmaxf(t1, t2));
                    lsum += p[u];
                }
                *(uint4*)((char*)Ap + swz128(prow, pjh * 2 + q)) =
                    make_uint4(pack2(p[0], p[1]), pack2(p[2], p[3]),
                               pack2(p[4], p[5]), pack2(p[6], p[7]));
            }
        }
        __syncthreads();   // drains vmcnt (global_load_lds) + lgkm (Ap writes)
#pragma unroll
        for (int kk = 0; kk < 2; kk++) {
            half8 af[4], bf[4];
#pragma unroll
            for (int a = 0; a < 4; a++)
                af[a] = *(const half8*)((char*)Ap + swz128(wi * 64 + a * 16 + l15, kk * 4 + quad));
#pragma unroll
            for (int c = 0; c < 4; c++)
                bf[c] = *(const half8*)((char*)Bp + swz128(wo * 64 + c * 16 + l15, kk * 4 + quad));
#pragma unroll
            for (int a = 0; a < 4; a++)
#pragma unroll
                for (int c = 0; c < 4; c++)
                    acc[a][c] = __builtin_amdgcn_mfma_f32_16x16x32_f16(af[a], bf[c], acc[a][c], 0, 0, 0);
        }
    }

    // fold the 4 per-row P-gen threads' partial sums (lanes 4r..4r+3)
    lsum += __shfl_xor(lsum, 1, 64);
    lsum += __shfl_xor(lsum, 2, 64);
    __syncthreads();   // Ap/Bp reads done before lns overlay write below
    if (pjh == 0) lns[prow] = lsum;
    __syncthreads();

    // rs = -L2E / l  (raw v_rcp; rel err ~1e-5 << tolerance)
    float rs[4][4];
#pragma unroll
    for (int a = 0; a < 4; a++)
#pragma unroll
        for (int r = 0; r < 4; r++)
            rs[a][r] = -L2E * RCPF(lns[wi * 64 + a * 16 + quad * 4 + r]);

#pragma unroll
    for (int a = 0; a < 4; a++) {
#pragma unroll
        for (int c = 0; c < 4; c++) {
            int o = wo * 64 + c * 16 + l15;
#pragma unroll
            for (int r = 0; r < 4; r++) {
                int i = i0 + wi * 64 + a * 16 + quad * 4 + r;
                // sigmoid(relu(v)) = rcp(1 + exp2(min(v*(-L2E/l), 0)))
                float tx = fminf(acc[a][c][r] * rs[a][r], 0.0f);
                float y = RCPF(1.0f + EXP2F(tx));
                out[((size_t)(b * 1024 + i) << 11) + head * 256 + o] = y;
            }
        }
    }
}

// ---------------------------------------------------------------------------
extern "C" void kernel_launch(void* const* d_in, const int* in_sizes, int n_in,
                              void* d_out, int out_size, void* d_ws, size_t ws_size,
                              hipStream_t stream)
{
    const float* h  = (const float*)d_in[0];
    const float* W  = (const float*)d_in[1];
    const float* bW = (const float*)d_in[2];
    const float* a1 = (const float*)d_in[3];
    const float* a2 = (const float*)d_in[4];
    const float* bA = (const float*)d_in[5];
    float* out = (float*)d_out;

    char* ws = (char*)d_ws;
    _Float16* WhT = (_Float16*)ws;                       // 67108864 B
    float* eiP = (float*)(ws + 67108864);                // 2 x 524288 B
    float* ejP = (float*)(ws + 67108864 + 1048576);      // 2 x 524288 B

    hipLaunchKernelGGL(wh_kernel, dim3(128, 2, 8), dim3(256), 0, stream,
                       h, W, bW, WhT, a1, a2, eiP, ejP);
    hipLaunchKernelGGL(pv_kernel, dim3(128, 4), dim3(1024), 0, stream,
                       WhT, eiP, ejP, bA, out);
}